// Round 1
// baseline (655.475 us; speedup 1.0000x reference)
//
#include <hip/hip_runtime.h>

#define PI_2F 1.5707963267948966f
#define NV 400000
#define NF 200000
#define NM 9

// out layout (floats): verts [0, 10.8M), faces [10.8M, 16.2M), atlas [16.2M, 102.6M)
#define VERTS_OFF 0
#define FACES_OFF 10800000
#define ATLAS_OFF 16200000
#define N_FACE_F4 1350000      // 9*200000*3 / 4
#define FACE_F4_PER_M 150000   // 200000*3 / 4
#define N_ATLAS_F4 21600000    // 9*200000*4*4*3 / 4

__device__ __forceinline__ void matmul4(const float* A, const float* B, float* C) {
    #pragma unroll
    for (int r = 0; r < 4; ++r)
        #pragma unroll
        for (int c = 0; c < 4; ++c) {
            float s = 0.f;
            #pragma unroll
            for (int k = 0; k < 4; ++k) s += A[r*4+k]*B[k*4+c];
            C[r*4+c] = s;
        }
}

__device__ __forceinline__ void dh(float alpha, float a, float theta, float d, float* M) {
    float ca = cosf(alpha), sa = sinf(alpha);
    float ct = cosf(theta), st = sinf(theta);
    M[0]=ct;    M[1]=-st;   M[2]=0.f;  M[3]=a;
    M[4]=st*ca; M[5]=ct*ca; M[6]=-sa;  M[7]=-d*sa;
    M[8]=st*sa; M[9]=ct*sa; M[10]=ca;  M[11]=d*ca;
    M[12]=0.f;  M[13]=0.f;  M[14]=0.f; M[15]=1.f;
}

// Single-thread FK: writes 9 transforms (3 rows x 4 cols each = 12 floats) into ws.
__global__ void fk_kernel(const float* __restrict__ jp,
                          const float* __restrict__ baseT,
                          const float* __restrict__ linkM,
                          const float* __restrict__ toolM,
                          float* __restrict__ ws) {
    if (threadIdx.x != 0 || blockIdx.x != 0) return;
    const float alpha[7] = {PI_2F, -PI_2F, PI_2F, 0.f, -PI_2F, -PI_2F, -PI_2F};
    const float aarr[7]  = {0.f, 0.f, 0.f, 0.f, 0.f, 0.091f, 0.f};
    const float d0arr[7] = {0.f, 0.f, 0.f, 4.16f, 0.f, 0.f, 0.106f};
    const float off[7]   = {PI_2F, -PI_2F, -4.389f, 0.f, -PI_2F, -PI_2F, PI_2F};
    const int   prism[7] = {0, 0, 1, 0, 0, 0, 0};

    float j[7];
    #pragma unroll
    for (int i = 0; i < 6; ++i) j[i] = jp[i];
    j[6] = 0.f;
    float tool_angle = jp[6] * PI_2F;

    float T[16];     // T_N_0
    #pragma unroll
    for (int i = 0; i < 16; ++i) T[i] = (i % 5 == 0) ? 1.f : 0.f;
    float Trans[16];
    #pragma unroll
    for (int i = 0; i < 16; ++i) Trans[i] = baseT[i];

    float M[16], tmp[16], tmp2[16];
    for (int i = 0; i < 7; ++i) {
        #pragma unroll
        for (int k = 0; k < 12; ++k) ws[i*12 + k] = Trans[k];
        if (prism[i]) dh(alpha[i], aarr[i], 0.f, j[i] + off[i], M);
        else          dh(alpha[i], aarr[i], j[i] + off[i], d0arr[i], M);
        matmul4(T, M, tmp);
        #pragma unroll
        for (int k = 0; k < 16; ++k) T[k] = tmp[k];
        matmul4(T, linkM + i*16, tmp);
        matmul4(baseT, tmp, Trans);
    }
    for (int t = 0; t < 2; ++t) {
        float ang = (t == 0) ? -tool_angle : tool_angle;
        dh(0.f, 0.f, ang, 0.f, M);
        matmul4(T, toolM + t*16, tmp);
        matmul4(tmp, M, tmp2);
        matmul4(baseT, tmp2, tmp);
        #pragma unroll
        for (int k = 0; k < 12; ++k) ws[(7+t)*12 + k] = tmp[k];
    }
}

// One thread per vertex: out = R_m * p + t_m
__global__ void vert_kernel(const float* __restrict__ vin,
                            const float* __restrict__ ws,
                            float* __restrict__ out) {
    __shared__ float Ts[108];
    if (threadIdx.x < 108) Ts[threadIdx.x] = ws[threadIdx.x];
    __syncthreads();
    int v = blockIdx.x * blockDim.x + threadIdx.x;
    if (v >= NM * NV) return;
    int m = v / NV;
    const float* T = &Ts[m * 12];
    float x = vin[3*v + 0], y = vin[3*v + 1], z = vin[3*v + 2];
    out[3*v + 0] = fmaf(T[0], x, fmaf(T[1], y, fmaf(T[2],  z, T[3])));
    out[3*v + 1] = fmaf(T[4], x, fmaf(T[5], y, fmaf(T[6],  z, T[7])));
    out[3*v + 2] = fmaf(T[8], x, fmaf(T[9], y, fmaf(T[10], z, T[11])));
}

// faces: float4 add of m*V; 150000 float4 per mesh -> each float4 single-mesh
__global__ void faces_kernel(const float4* __restrict__ fin,
                             float4* __restrict__ fout) {
    int i = blockIdx.x * blockDim.x + threadIdx.x;
    if (i >= N_FACE_F4) return;
    int m = i / FACE_F4_PER_M;
    float add = (float)(m * NV);
    float4 v = fin[i];
    v.x += add; v.y += add; v.z += add; v.w += add;
    fout[i] = v;
}

// atlas: pure float4 copy
__global__ void atlas_kernel(const float4* __restrict__ ain,
                             float4* __restrict__ aout) {
    int i = blockIdx.x * blockDim.x + threadIdx.x;
    if (i >= N_ATLAS_F4) return;
    aout[i] = ain[i];
}

extern "C" void kernel_launch(void* const* d_in, const int* in_sizes, int n_in,
                              void* d_out, int out_size, void* d_ws, size_t ws_size,
                              hipStream_t stream) {
    const float* jp    = (const float*)d_in[0];
    const float* baseT = (const float*)d_in[1];
    const float* linkM = (const float*)d_in[2];
    const float* toolM = (const float*)d_in[3];
    const float* vin   = (const float*)d_in[4];
    const float* fin   = (const float*)d_in[5];
    const float* ain   = (const float*)d_in[6];
    float* out = (float*)d_out;
    float* ws  = (float*)d_ws;

    fk_kernel<<<1, 64, 0, stream>>>(jp, baseT, linkM, toolM, ws);
    vert_kernel<<<(NM*NV + 255)/256, 256, 0, stream>>>(vin, ws, out + VERTS_OFF);
    faces_kernel<<<(N_FACE_F4 + 255)/256, 256, 0, stream>>>(
        (const float4*)fin, (float4*)(out + FACES_OFF));
    atlas_kernel<<<(N_ATLAS_F4 + 255)/256, 256, 0, stream>>>(
        (const float4*)ain, (float4*)(out + ATLAS_OFF));
}